// Round 1
// baseline (776.818 us; speedup 1.0000x reference)
//
#include <hip/hip_runtime.h>
#include <hip/hip_bf16.h>

#define NN 100000
#define NE 800000
#define DIM 96
#define NEG_SLOPE 0.01f

// ---------------- CSR build ----------------

__global__ __launch_bounds__(256) void hist_kernel(const int* __restrict__ src, int* __restrict__ deg) {
    int e = blockIdx.x * 256 + threadIdx.x;
    if (e < NE) atomicAdd(&deg[src[e]], 1);
}

__global__ __launch_bounds__(1024) void scan_kernel(const int* __restrict__ deg, int* __restrict__ row_ptr,
                                                    int* __restrict__ cursor) {
    __shared__ int lds[1024];
    const int i = threadIdx.x;
    const int chunk = (NN + 1023) / 1024;   // 98
    const int base = i * chunk;
    int sum = 0;
    for (int j = 0; j < chunk; j++) {
        int idx = base + j;
        if (idx < NN) sum += deg[idx];
    }
    lds[i] = sum;
    __syncthreads();
    // Hillis-Steele inclusive scan over 1024 partials
    for (int off = 1; off < 1024; off <<= 1) {
        int v = (i >= off) ? lds[i - off] : 0;
        __syncthreads();
        lds[i] += v;
        __syncthreads();
    }
    int run = lds[i] - sum;   // exclusive prefix for this chunk
    for (int j = 0; j < chunk; j++) {
        int idx = base + j;
        if (idx < NN) {
            int d = deg[idx];
            row_ptr[idx] = run;
            cursor[idx]  = run;
            run += d;
        }
    }
    if (i == 0) row_ptr[NN] = NE;
}

__global__ __launch_bounds__(256) void fill_kernel(const int* __restrict__ src, const int* __restrict__ dst,
                                                   int* __restrict__ cursor, int* __restrict__ dst_perm) {
    int e = blockIdx.x * 256 + threadIdx.x;
    if (e < NE) {
        int s = src[e];
        int pos = atomicAdd(&cursor[s], 1);
        dst_perm[pos] = dst[e];
    }
}

// ---------------- GEMM: C[N,96] = A[N,96] @ W[96,96] ----------------
// block = (24,8) = 192 threads, 64 rows per block, thread tile 8 rows x 4 cols.

__global__ __launch_bounds__(192) void gemm96_kernel(const float* __restrict__ A, const float* __restrict__ W,
                                                     float* __restrict__ C, int n) {
    __shared__ float Ws[96 * 100];   // [k][c], padded stride 100
    __shared__ float As[64 * 100];   // [r][k], padded stride 100
    const int tx = threadIdx.x;      // 0..23
    const int ty = threadIdx.y;      // 0..7
    const int t  = ty * 24 + tx;     // 0..191
    const int row0 = blockIdx.x * 64;

    // stage W: 2304 float4
    for (int q = t; q < 2304; q += 192) {
        int k = q / 24, c4 = q % 24;
        float4 v = ((const float4*)W)[q];
        *(float4*)&Ws[k * 100 + c4 * 4] = v;
    }
    // stage A rows: 1536 float4
    for (int q = t; q < 1536; q += 192) {
        int r = q / 24, c4 = q % 24;
        int gr = row0 + r;
        float4 v = make_float4(0.f, 0.f, 0.f, 0.f);
        if (gr < n) v = *(const float4*)(A + (size_t)gr * DIM + c4 * 4);
        *(float4*)&As[r * 100 + c4 * 4] = v;
    }
    __syncthreads();

    float acc[8][4];
#pragma unroll
    for (int i = 0; i < 8; i++)
#pragma unroll
        for (int j = 0; j < 4; j++) acc[i][j] = 0.f;

    const int r0 = ty * 8, c0 = tx * 4;
    for (int k = 0; k < 96; k += 4) {
        float4 w0 = *(const float4*)&Ws[(k + 0) * 100 + c0];
        float4 w1 = *(const float4*)&Ws[(k + 1) * 100 + c0];
        float4 w2 = *(const float4*)&Ws[(k + 2) * 100 + c0];
        float4 w3 = *(const float4*)&Ws[(k + 3) * 100 + c0];
#pragma unroll
        for (int i = 0; i < 8; i++) {
            float4 a = *(const float4*)&As[(r0 + i) * 100 + k];
            acc[i][0] = fmaf(a.x, w0.x, fmaf(a.y, w1.x, fmaf(a.z, w2.x, fmaf(a.w, w3.x, acc[i][0]))));
            acc[i][1] = fmaf(a.x, w0.y, fmaf(a.y, w1.y, fmaf(a.z, w2.y, fmaf(a.w, w3.y, acc[i][1]))));
            acc[i][2] = fmaf(a.x, w0.z, fmaf(a.y, w1.z, fmaf(a.z, w2.z, fmaf(a.w, w3.z, acc[i][2]))));
            acc[i][3] = fmaf(a.x, w0.w, fmaf(a.y, w1.w, fmaf(a.z, w2.w, fmaf(a.w, w3.w, acc[i][3]))));
        }
    }

#pragma unroll
    for (int i = 0; i < 8; i++) {
        int gr = row0 + r0 + i;
        if (gr < n) {
            *(float4*)(C + (size_t)gr * DIM + c0) = make_float4(acc[i][0], acc[i][1], acc[i][2], acc[i][3]);
        }
    }
}

// ---------------- per-node attention dots: ssrc[n]=h[n]·a[:96], sdst[n]=h[n]·a[96:] ----------------
// one wave per node

__global__ __launch_bounds__(256) void dots_kernel(const float* __restrict__ h, const float* __restrict__ a,
                                                   float* __restrict__ ssrc, float* __restrict__ sdst) {
    int gid  = blockIdx.x * 256 + threadIdx.x;
    int node = gid >> 6;
    int lane = threadIdx.x & 63;
    if (node >= NN) return;
    const float* hr = h + (size_t)node * DIM;
    float v0 = hr[lane];
    float v1 = (lane < 32) ? hr[64 + lane] : 0.f;
    float a0 = a[lane];
    float a1v = (lane < 32) ? a[64 + lane] : 0.f;
    float b0 = a[96 + lane];
    float b1 = (lane < 32) ? a[160 + lane] : 0.f;
    float ps = v0 * a0 + v1 * a1v;
    float pd = v0 * b0 + v1 * b1;
    for (int off = 32; off > 0; off >>= 1) {
        ps += __shfl_down(ps, off);
        pd += __shfl_down(pd, off);
    }
    if (lane == 0) {
        ssrc[node] = ps;
        sdst[node] = pd;
    }
}

// ---------------- CSR aggregation: out[n] = (sum_e w_e * h[dst_e]) / (sum_e w_e) ----------------
// one wave per node; lane covers feature lane (and 64+lane for lane<32)

template <bool RELU>
__global__ __launch_bounds__(256) void agg_kernel(const float* __restrict__ h, const float* __restrict__ ssrc,
                                                  const float* __restrict__ sdst, const int* __restrict__ row_ptr,
                                                  const int* __restrict__ dst_perm, float* __restrict__ out) {
    int gid  = blockIdx.x * 256 + threadIdx.x;
    int node = gid >> 6;
    int lane = threadIdx.x & 63;
    if (node >= NN) return;
    int start = row_ptr[node];
    int end   = row_ptr[node + 1];
    float ss  = ssrc[node];
    float acc0 = 0.f, acc1 = 0.f, wsum = 0.f;
    for (int p = start; p < end; p++) {
        int d = dst_perm[p];
        float s  = ss + sdst[d];
        float lr = s > 0.f ? s : NEG_SLOPE * s;
        float wgt = __expf(-lr);
        wsum += wgt;
        const float* hr = h + (size_t)d * DIM;
        acc0 += wgt * hr[lane];
        if (lane < 32) acc1 += wgt * hr[64 + lane];
    }
    float inv = 1.f / wsum;
    float r0 = acc0 * inv;
    float r1 = acc1 * inv;
    if (RELU) {
        r0 = fmaxf(r0, 0.f);
        r1 = fmaxf(r1, 0.f);
    }
    float* orow = out + (size_t)node * DIM;
    orow[lane] = r0;
    if (lane < 32) orow[64 + lane] = r1;
}

// ---------------- launch ----------------

extern "C" void kernel_launch(void* const* d_in, const int* in_sizes, int n_in,
                              void* d_out, int out_size, void* d_ws, size_t ws_size,
                              hipStream_t stream) {
    (void)in_sizes; (void)n_in; (void)out_size; (void)ws_size;
    const int*   edge_index = (const int*)d_in[0];
    const float* x  = (const float*)d_in[1];
    const float* W1 = (const float*)d_in[2];
    const float* a1 = (const float*)d_in[3];
    const float* W2 = (const float*)d_in[4];
    const float* a2 = (const float*)d_in[5];
    float* out = (float*)d_out;

    const int* src = edge_index;
    const int* dst = edge_index + NE;

    char* ws = (char*)d_ws;
    size_t off = 0;
    auto alloc = [&](size_t bytes) -> void* {
        void* p = ws + off;
        off += (bytes + 255) & ~(size_t)255;
        return p;
    };
    float* hA       = (float*)alloc((size_t)NN * DIM * 4);
    float* hB       = (float*)alloc((size_t)NN * DIM * 4);
    float* ssrc     = (float*)alloc((size_t)NN * 4);
    float* sdst     = (float*)alloc((size_t)NN * 4);
    int*   deg      = (int*)alloc((size_t)NN * 4);
    int*   row_ptr  = (int*)alloc((size_t)(NN + 1) * 4);
    int*   cursor   = (int*)alloc((size_t)NN * 4);
    int*   dst_perm = (int*)alloc((size_t)NE * 4);

    // ---- build CSR (per launch; ws is re-poisoned between calls) ----
    hipMemsetAsync(deg, 0, (size_t)NN * 4, stream);
    hist_kernel<<<(NE + 255) / 256, 256, 0, stream>>>(src, deg);
    scan_kernel<<<1, 1024, 0, stream>>>(deg, row_ptr, cursor);
    fill_kernel<<<(NE + 255) / 256, 256, 0, stream>>>(src, dst, cursor, dst_perm);

    dim3 gemm_block(24, 8);
    int gemm_grid   = (NN + 63) / 64;                 // 1563
    int wave_blocks = ((NN * 64) + 255) / 256;        // 25000 (one wave per node)

    // ---- layer 1 ----
    gemm96_kernel<<<gemm_grid, gemm_block, 0, stream>>>(x, W1, hA, NN);
    dots_kernel<<<wave_blocks, 256, 0, stream>>>(hA, a1, ssrc, sdst);
    agg_kernel<false><<<wave_blocks, 256, 0, stream>>>(hA, ssrc, sdst, row_ptr, dst_perm, hB);

    // ---- layer 2 ----
    gemm96_kernel<<<gemm_grid, gemm_block, 0, stream>>>(hB, W2, hA, NN);
    dots_kernel<<<wave_blocks, 256, 0, stream>>>(hA, a2, ssrc, sdst);
    agg_kernel<true><<<wave_blocks, 256, 0, stream>>>(hA, ssrc, sdst, row_ptr, dst_perm, out);
}

// Round 2
// 524.666 us; speedup vs baseline: 1.4806x; 1.4806x over previous
//
#include <hip/hip_runtime.h>
#include <hip/hip_bf16.h>

#define NN 100000
#define NE 800000
#define DIM 96
#define NEG_SLOPE 0.01f
#define SCAN_BLOCKS ((NN + 255) / 256)   // 391

// ---------------- CSR build ----------------

__global__ __launch_bounds__(256) void hist_kernel(const int* __restrict__ src, int* __restrict__ deg) {
    int e = blockIdx.x * 256 + threadIdx.x;
    if (e < NE) atomicAdd(&deg[src[e]], 1);
}

// phase 1: per-block sums of deg
__global__ __launch_bounds__(256) void partial_kernel(const int* __restrict__ deg, int* __restrict__ blocksum) {
    __shared__ int lds[4];
    int idx = blockIdx.x * 256 + threadIdx.x;
    int v = (idx < NN) ? deg[idx] : 0;
    // wave reduce
    for (int off = 32; off > 0; off >>= 1) v += __shfl_down(v, off);
    int wave = threadIdx.x >> 6;
    int lane = threadIdx.x & 63;
    if (lane == 0) lds[wave] = v;
    __syncthreads();
    if (threadIdx.x == 0) blocksum[blockIdx.x] = lds[0] + lds[1] + lds[2] + lds[3];
}

// phase 2: exclusive scan of SCAN_BLOCKS partials (single block)
__global__ __launch_bounds__(512) void scan_partials_kernel(const int* __restrict__ blocksum, int* __restrict__ blockoff) {
    __shared__ int lds[512];
    int i = threadIdx.x;
    int v = (i < SCAN_BLOCKS) ? blocksum[i] : 0;
    lds[i] = v;
    __syncthreads();
    for (int off = 1; off < 512; off <<= 1) {
        int t = (i >= off) ? lds[i - off] : 0;
        __syncthreads();
        lds[i] += t;
        __syncthreads();
    }
    if (i < SCAN_BLOCKS) blockoff[i] = lds[i] - v;   // exclusive
}

// phase 3: block-local exclusive scan + block offset -> row_ptr, cursor
__global__ __launch_bounds__(256) void rowptr_kernel(const int* __restrict__ deg, const int* __restrict__ blockoff,
                                                     int* __restrict__ row_ptr, int* __restrict__ cursor) {
    __shared__ int lds[256];
    int i = threadIdx.x;
    int idx = blockIdx.x * 256 + i;
    int v = (idx < NN) ? deg[idx] : 0;
    lds[i] = v;
    __syncthreads();
    for (int off = 1; off < 256; off <<= 1) {
        int t = (i >= off) ? lds[i - off] : 0;
        __syncthreads();
        lds[i] += t;
        __syncthreads();
    }
    if (idx < NN) {
        int r = blockoff[blockIdx.x] + lds[i] - v;   // exclusive prefix
        row_ptr[idx] = r;
        cursor[idx]  = r;
    }
    if (idx == 0) row_ptr[NN] = NE;
}

__global__ __launch_bounds__(256) void fill_kernel(const int* __restrict__ src, const int* __restrict__ dst,
                                                   int* __restrict__ cursor, int* __restrict__ dst_perm) {
    int e = blockIdx.x * 256 + threadIdx.x;
    if (e < NE) {
        int s = src[e];
        int pos = atomicAdd(&cursor[s], 1);
        dst_perm[pos] = dst[e];
    }
}

// ---------------- GEMM: C[N,96] = A[N,96] @ W[96,96] ----------------
// block = (24,8) = 192 threads, 64 rows per block, thread tile 8 rows x 4 cols.

__global__ __launch_bounds__(192) void gemm96_kernel(const float* __restrict__ A, const float* __restrict__ W,
                                                     float* __restrict__ C, int n) {
    __shared__ float Ws[96 * 100];   // [k][c], padded stride 100
    __shared__ float As[64 * 100];   // [r][k], padded stride 100
    const int tx = threadIdx.x;      // 0..23
    const int ty = threadIdx.y;      // 0..7
    const int t  = ty * 24 + tx;     // 0..191
    const int row0 = blockIdx.x * 64;

    // stage W: 2304 float4
    for (int q = t; q < 2304; q += 192) {
        int k = q / 24, c4 = q % 24;
        float4 v = ((const float4*)W)[q];
        *(float4*)&Ws[k * 100 + c4 * 4] = v;
    }
    // stage A rows: 1536 float4
    for (int q = t; q < 1536; q += 192) {
        int r = q / 24, c4 = q % 24;
        int gr = row0 + r;
        float4 v = make_float4(0.f, 0.f, 0.f, 0.f);
        if (gr < n) v = *(const float4*)(A + (size_t)gr * DIM + c4 * 4);
        *(float4*)&As[r * 100 + c4 * 4] = v;
    }
    __syncthreads();

    float acc[8][4];
#pragma unroll
    for (int i = 0; i < 8; i++)
#pragma unroll
        for (int j = 0; j < 4; j++) acc[i][j] = 0.f;

    const int r0 = ty * 8, c0 = tx * 4;
    for (int k = 0; k < 96; k += 4) {
        float4 w0 = *(const float4*)&Ws[(k + 0) * 100 + c0];
        float4 w1 = *(const float4*)&Ws[(k + 1) * 100 + c0];
        float4 w2 = *(const float4*)&Ws[(k + 2) * 100 + c0];
        float4 w3 = *(const float4*)&Ws[(k + 3) * 100 + c0];
#pragma unroll
        for (int i = 0; i < 8; i++) {
            float4 a = *(const float4*)&As[(r0 + i) * 100 + k];
            acc[i][0] = fmaf(a.x, w0.x, fmaf(a.y, w1.x, fmaf(a.z, w2.x, fmaf(a.w, w3.x, acc[i][0]))));
            acc[i][1] = fmaf(a.x, w0.y, fmaf(a.y, w1.y, fmaf(a.z, w2.y, fmaf(a.w, w3.y, acc[i][1]))));
            acc[i][2] = fmaf(a.x, w0.z, fmaf(a.y, w1.z, fmaf(a.z, w2.z, fmaf(a.w, w3.z, acc[i][2]))));
            acc[i][3] = fmaf(a.x, w0.w, fmaf(a.y, w1.w, fmaf(a.z, w2.w, fmaf(a.w, w3.w, acc[i][3]))));
        }
    }

#pragma unroll
    for (int i = 0; i < 8; i++) {
        int gr = row0 + r0 + i;
        if (gr < n) {
            *(float4*)(C + (size_t)gr * DIM + c0) = make_float4(acc[i][0], acc[i][1], acc[i][2], acc[i][3]);
        }
    }
}

// ---------------- per-node attention dots: ssrc[n]=h[n]·a[:96], sdst[n]=h[n]·a[96:] ----------------
// one wave per node

__global__ __launch_bounds__(256) void dots_kernel(const float* __restrict__ h, const float* __restrict__ a,
                                                   float* __restrict__ ssrc, float* __restrict__ sdst) {
    int gid  = blockIdx.x * 256 + threadIdx.x;
    int node = gid >> 6;
    int lane = threadIdx.x & 63;
    if (node >= NN) return;
    const float* hr = h + (size_t)node * DIM;
    float v0 = hr[lane];
    float v1 = (lane < 32) ? hr[64 + lane] : 0.f;
    float a0 = a[lane];
    float a1v = (lane < 32) ? a[64 + lane] : 0.f;
    float b0 = a[96 + lane];
    float b1 = (lane < 32) ? a[160 + lane] : 0.f;
    float ps = v0 * a0 + v1 * a1v;
    float pd = v0 * b0 + v1 * b1;
    for (int off = 32; off > 0; off >>= 1) {
        ps += __shfl_down(ps, off);
        pd += __shfl_down(pd, off);
    }
    if (lane == 0) {
        ssrc[node] = ps;
        sdst[node] = pd;
    }
}

// ---------------- CSR aggregation: out[n] = (sum_e w_e * h[dst_e]) / (sum_e w_e) ----------------
// one wave per node; lane covers feature lane (and 64+lane for lane<32)

template <bool RELU>
__global__ __launch_bounds__(256) void agg_kernel(const float* __restrict__ h, const float* __restrict__ ssrc,
                                                  const float* __restrict__ sdst, const int* __restrict__ row_ptr,
                                                  const int* __restrict__ dst_perm, float* __restrict__ out) {
    int gid  = blockIdx.x * 256 + threadIdx.x;
    int node = gid >> 6;
    int lane = threadIdx.x & 63;
    if (node >= NN) return;
    int start = row_ptr[node];
    int end   = row_ptr[node + 1];
    float ss  = ssrc[node];
    float acc0 = 0.f, acc1 = 0.f, wsum = 0.f;
    for (int p = start; p < end; p++) {
        int d = dst_perm[p];
        float s  = ss + sdst[d];
        float lr = s > 0.f ? s : NEG_SLOPE * s;
        float wgt = __expf(-lr);
        wsum += wgt;
        const float* hr = h + (size_t)d * DIM;
        acc0 += wgt * hr[lane];
        if (lane < 32) acc1 += wgt * hr[64 + lane];
    }
    float inv = 1.f / wsum;
    float r0 = acc0 * inv;
    float r1 = acc1 * inv;
    if (RELU) {
        r0 = fmaxf(r0, 0.f);
        r1 = fmaxf(r1, 0.f);
    }
    float* orow = out + (size_t)node * DIM;
    orow[lane] = r0;
    if (lane < 32) orow[64 + lane] = r1;
}

// ---------------- launch ----------------

extern "C" void kernel_launch(void* const* d_in, const int* in_sizes, int n_in,
                              void* d_out, int out_size, void* d_ws, size_t ws_size,
                              hipStream_t stream) {
    (void)in_sizes; (void)n_in; (void)out_size; (void)ws_size;
    const int*   edge_index = (const int*)d_in[0];
    const float* x  = (const float*)d_in[1];
    const float* W1 = (const float*)d_in[2];
    const float* a1 = (const float*)d_in[3];
    const float* W2 = (const float*)d_in[4];
    const float* a2 = (const float*)d_in[5];
    float* out = (float*)d_out;

    const int* src = edge_index;
    const int* dst = edge_index + NE;

    char* ws = (char*)d_ws;
    size_t off = 0;
    auto alloc = [&](size_t bytes) -> void* {
        void* p = ws + off;
        off += (bytes + 255) & ~(size_t)255;
        return p;
    };
    float* hA       = (float*)alloc((size_t)NN * DIM * 4);
    float* hB       = (float*)alloc((size_t)NN * DIM * 4);
    float* ssrc     = (float*)alloc((size_t)NN * 4);
    float* sdst     = (float*)alloc((size_t)NN * 4);
    int*   deg      = (int*)alloc((size_t)NN * 4);
    int*   row_ptr  = (int*)alloc((size_t)(NN + 1) * 4);
    int*   cursor   = (int*)alloc((size_t)NN * 4);
    int*   dst_perm = (int*)alloc((size_t)NE * 4);
    int*   blocksum = (int*)alloc((size_t)SCAN_BLOCKS * 4);
    int*   blockoff = (int*)alloc((size_t)SCAN_BLOCKS * 4);

    // ---- build CSR (per launch; ws is re-poisoned between calls) ----
    hipMemsetAsync(deg, 0, (size_t)NN * 4, stream);
    hist_kernel<<<(NE + 255) / 256, 256, 0, stream>>>(src, deg);
    partial_kernel<<<SCAN_BLOCKS, 256, 0, stream>>>(deg, blocksum);
    scan_partials_kernel<<<1, 512, 0, stream>>>(blocksum, blockoff);
    rowptr_kernel<<<SCAN_BLOCKS, 256, 0, stream>>>(deg, blockoff, row_ptr, cursor);
    fill_kernel<<<(NE + 255) / 256, 256, 0, stream>>>(src, dst, cursor, dst_perm);

    dim3 gemm_block(24, 8);
    int gemm_grid   = (NN + 63) / 64;                 // 1563
    int wave_blocks = ((NN * 64) + 255) / 256;        // 25000 (one wave per node)

    // ---- layer 1 ----
    gemm96_kernel<<<gemm_grid, gemm_block, 0, stream>>>(x, W1, hA, NN);
    dots_kernel<<<wave_blocks, 256, 0, stream>>>(hA, a1, ssrc, sdst);
    agg_kernel<false><<<wave_blocks, 256, 0, stream>>>(hA, ssrc, sdst, row_ptr, dst_perm, hB);

    // ---- layer 2 ----
    gemm96_kernel<<<gemm_grid, gemm_block, 0, stream>>>(hB, W2, hA, NN);
    dots_kernel<<<wave_blocks, 256, 0, stream>>>(hA, a2, ssrc, sdst);
    agg_kernel<true><<<wave_blocks, 256, 0, stream>>>(hA, ssrc, sdst, row_ptr, dst_perm, out);
}

// Round 3
// 407.166 us; speedup vs baseline: 1.9079x; 1.2886x over previous
//
#include <hip/hip_runtime.h>
#include <hip/hip_bf16.h>

#define NN 100000
#define NE 800000
#define DIM 96
#define NEG_SLOPE 0.01f
#define SCAN_BLOCKS ((NN + 255) / 256)   // 391

// ---------------- CSR build ----------------

__global__ __launch_bounds__(256) void hist_kernel(const int* __restrict__ src, int* __restrict__ deg) {
    int e = blockIdx.x * 256 + threadIdx.x;
    if (e < NE) atomicAdd(&deg[src[e]], 1);
}

// phase 1: per-block sums of deg
__global__ __launch_bounds__(256) void partial_kernel(const int* __restrict__ deg, int* __restrict__ blocksum) {
    __shared__ int lds[4];
    int idx = blockIdx.x * 256 + threadIdx.x;
    int v = (idx < NN) ? deg[idx] : 0;
    for (int off = 32; off > 0; off >>= 1) v += __shfl_down(v, off);
    int wave = threadIdx.x >> 6;
    int lane = threadIdx.x & 63;
    if (lane == 0) lds[wave] = v;
    __syncthreads();
    if (threadIdx.x == 0) blocksum[blockIdx.x] = lds[0] + lds[1] + lds[2] + lds[3];
}

// phase 2: exclusive scan of SCAN_BLOCKS partials (single block)
__global__ __launch_bounds__(512) void scan_partials_kernel(const int* __restrict__ blocksum, int* __restrict__ blockoff) {
    __shared__ int lds[512];
    int i = threadIdx.x;
    int v = (i < SCAN_BLOCKS) ? blocksum[i] : 0;
    lds[i] = v;
    __syncthreads();
    for (int off = 1; off < 512; off <<= 1) {
        int t = (i >= off) ? lds[i - off] : 0;
        __syncthreads();
        lds[i] += t;
        __syncthreads();
    }
    if (i < SCAN_BLOCKS) blockoff[i] = lds[i] - v;   // exclusive
}

// phase 3: block-local exclusive scan + block offset -> row_ptr, cursor
__global__ __launch_bounds__(256) void rowptr_kernel(const int* __restrict__ deg, const int* __restrict__ blockoff,
                                                     int* __restrict__ row_ptr, int* __restrict__ cursor) {
    __shared__ int lds[256];
    int i = threadIdx.x;
    int idx = blockIdx.x * 256 + i;
    int v = (idx < NN) ? deg[idx] : 0;
    lds[i] = v;
    __syncthreads();
    for (int off = 1; off < 256; off <<= 1) {
        int t = (i >= off) ? lds[i - off] : 0;
        __syncthreads();
        lds[i] += t;
        __syncthreads();
    }
    if (idx < NN) {
        int r = blockoff[blockIdx.x] + lds[i] - v;   // exclusive prefix
        row_ptr[idx] = r;
        cursor[idx]  = r;
    }
    if (idx == 0) row_ptr[NN] = NE;
}

// scatter {src,dst} pairs into CSR order
__global__ __launch_bounds__(256) void fill_kernel(const int* __restrict__ src, const int* __restrict__ dst,
                                                   int* __restrict__ cursor, int2* __restrict__ sd_pairs) {
    int e = blockIdx.x * 256 + threadIdx.x;
    if (e < NE) {
        int s = src[e];
        int pos = atomicAdd(&cursor[s], 1);
        sd_pairs[pos] = make_int2(s, dst[e]);
    }
}

// ---------------- GEMM: C[N,96] = A[N,96] @ W[96,96] ----------------

__global__ __launch_bounds__(192) void gemm96_kernel(const float* __restrict__ A, const float* __restrict__ W,
                                                     float* __restrict__ C, int n) {
    __shared__ float Ws[96 * 100];   // [k][c], padded stride 100
    __shared__ float As[64 * 100];   // [r][k], padded stride 100
    const int tx = threadIdx.x;      // 0..23
    const int ty = threadIdx.y;      // 0..7
    const int t  = ty * 24 + tx;     // 0..191
    const int row0 = blockIdx.x * 64;

    for (int q = t; q < 2304; q += 192) {
        int k = q / 24, c4 = q % 24;
        float4 v = ((const float4*)W)[q];
        *(float4*)&Ws[k * 100 + c4 * 4] = v;
    }
    for (int q = t; q < 1536; q += 192) {
        int r = q / 24, c4 = q % 24;
        int gr = row0 + r;
        float4 v = make_float4(0.f, 0.f, 0.f, 0.f);
        if (gr < n) v = *(const float4*)(A + (size_t)gr * DIM + c4 * 4);
        *(float4*)&As[r * 100 + c4 * 4] = v;
    }
    __syncthreads();

    float acc[8][4];
#pragma unroll
    for (int i = 0; i < 8; i++)
#pragma unroll
        for (int j = 0; j < 4; j++) acc[i][j] = 0.f;

    const int r0 = ty * 8, c0 = tx * 4;
    for (int k = 0; k < 96; k += 4) {
        float4 w0 = *(const float4*)&Ws[(k + 0) * 100 + c0];
        float4 w1 = *(const float4*)&Ws[(k + 1) * 100 + c0];
        float4 w2 = *(const float4*)&Ws[(k + 2) * 100 + c0];
        float4 w3 = *(const float4*)&Ws[(k + 3) * 100 + c0];
#pragma unroll
        for (int i = 0; i < 8; i++) {
            float4 a = *(const float4*)&As[(r0 + i) * 100 + k];
            acc[i][0] = fmaf(a.x, w0.x, fmaf(a.y, w1.x, fmaf(a.z, w2.x, fmaf(a.w, w3.x, acc[i][0]))));
            acc[i][1] = fmaf(a.x, w0.y, fmaf(a.y, w1.y, fmaf(a.z, w2.y, fmaf(a.w, w3.y, acc[i][1]))));
            acc[i][2] = fmaf(a.x, w0.z, fmaf(a.y, w1.z, fmaf(a.z, w2.z, fmaf(a.w, w3.z, acc[i][2]))));
            acc[i][3] = fmaf(a.x, w0.w, fmaf(a.y, w1.w, fmaf(a.z, w2.w, fmaf(a.w, w3.w, acc[i][3]))));
        }
    }

#pragma unroll
    for (int i = 0; i < 8; i++) {
        int gr = row0 + r0 + i;
        if (gr < n) {
            *(float4*)(C + (size_t)gr * DIM + c0) = make_float4(acc[i][0], acc[i][1], acc[i][2], acc[i][3]);
        }
    }
}

// ---------------- per-node attention dots ----------------

__global__ __launch_bounds__(256) void dots_kernel(const float* __restrict__ h, const float* __restrict__ a,
                                                   float* __restrict__ ssrc, float* __restrict__ sdst) {
    int gid  = blockIdx.x * 256 + threadIdx.x;
    int node = gid >> 6;
    int lane = threadIdx.x & 63;
    if (node >= NN) return;
    const float* hr = h + (size_t)node * DIM;
    float v0 = hr[lane];
    float v1 = (lane < 32) ? hr[64 + lane] : 0.f;
    float a0 = a[lane];
    float a1v = (lane < 32) ? a[64 + lane] : 0.f;
    float b0 = a[96 + lane];
    float b1 = (lane < 32) ? a[160 + lane] : 0.f;
    float ps = v0 * a0 + v1 * a1v;
    float pd = v0 * b0 + v1 * b1;
    for (int off = 32; off > 0; off >>= 1) {
        ps += __shfl_down(ps, off);
        pd += __shfl_down(pd, off);
    }
    if (lane == 0) {
        ssrc[node] = ps;
        sdst[node] = pd;
    }
}

// ---------------- edge weights (edge-parallel, permuted order) ----------------
// w_pairs[p] = { dst, bits(exp(-lrelu(ssrc[src]+sdst[dst]))) }

__global__ __launch_bounds__(256) void edgew_kernel(const int2* __restrict__ sd_pairs,
                                                    const float* __restrict__ ssrc, const float* __restrict__ sdst,
                                                    int2* __restrict__ w_pairs) {
    int p = blockIdx.x * 256 + threadIdx.x;
    if (p >= NE) return;
    int2 sd = sd_pairs[p];
    float s  = ssrc[sd.x] + sdst[sd.y];
    float lr = s > 0.f ? s : NEG_SLOPE * s;
    float w  = __expf(-lr);
    w_pairs[p] = make_int2(sd.y, __float_as_int(w));
}

// ---------------- CSR aggregation ----------------
// one wave per node; lane covers feature lane (and 64+lane for lane<32)

template <bool RELU>
__global__ __launch_bounds__(256) void agg_kernel(const float* __restrict__ h,
                                                  const int* __restrict__ row_ptr,
                                                  const int2* __restrict__ w_pairs,
                                                  float* __restrict__ out) {
    int gid  = blockIdx.x * 256 + threadIdx.x;
    int node = gid >> 6;
    int lane = threadIdx.x & 63;
    if (node >= NN) return;
    int start = row_ptr[node];
    int end   = row_ptr[node + 1];
    float acc0 = 0.f, acc1 = 0.f, wsum = 0.f;

    int p = start;
    for (; p + 4 <= end; p += 4) {
        int2 q0 = w_pairs[p + 0];
        int2 q1 = w_pairs[p + 1];
        int2 q2 = w_pairs[p + 2];
        int2 q3 = w_pairs[p + 3];
        const float* h0 = h + (size_t)q0.x * DIM;
        const float* h1 = h + (size_t)q1.x * DIM;
        const float* h2 = h + (size_t)q2.x * DIM;
        const float* h3 = h + (size_t)q3.x * DIM;
        float w0 = __int_as_float(q0.y), w1 = __int_as_float(q1.y);
        float w2 = __int_as_float(q2.y), w3 = __int_as_float(q3.y);
        float x0 = h0[lane], x1 = h1[lane], x2 = h2[lane], x3 = h3[lane];
        float y0 = 0.f, y1 = 0.f, y2 = 0.f, y3 = 0.f;
        if (lane < 32) {
            y0 = h0[64 + lane]; y1 = h1[64 + lane]; y2 = h2[64 + lane]; y3 = h3[64 + lane];
        }
        acc0 = fmaf(w0, x0, fmaf(w1, x1, fmaf(w2, x2, fmaf(w3, x3, acc0))));
        acc1 = fmaf(w0, y0, fmaf(w1, y1, fmaf(w2, y2, fmaf(w3, y3, acc1))));
        wsum += (w0 + w1) + (w2 + w3);
    }
    for (; p < end; p++) {
        int2 q = w_pairs[p];
        const float* hr = h + (size_t)q.x * DIM;
        float w = __int_as_float(q.y);
        wsum += w;
        acc0 = fmaf(w, hr[lane], acc0);
        if (lane < 32) acc1 = fmaf(w, hr[64 + lane], acc1);
    }

    float inv = 1.f / wsum;
    float r0 = acc0 * inv;
    float r1 = acc1 * inv;
    if (RELU) {
        r0 = fmaxf(r0, 0.f);
        r1 = fmaxf(r1, 0.f);
    }
    float* orow = out + (size_t)node * DIM;
    orow[lane] = r0;
    if (lane < 32) orow[64 + lane] = r1;
}

// ---------------- launch ----------------

extern "C" void kernel_launch(void* const* d_in, const int* in_sizes, int n_in,
                              void* d_out, int out_size, void* d_ws, size_t ws_size,
                              hipStream_t stream) {
    (void)in_sizes; (void)n_in; (void)out_size; (void)ws_size;
    const int*   edge_index = (const int*)d_in[0];
    const float* x  = (const float*)d_in[1];
    const float* W1 = (const float*)d_in[2];
    const float* a1 = (const float*)d_in[3];
    const float* W2 = (const float*)d_in[4];
    const float* a2 = (const float*)d_in[5];
    float* out = (float*)d_out;

    const int* src = edge_index;
    const int* dst = edge_index + NE;

    char* ws = (char*)d_ws;
    size_t off = 0;
    auto alloc = [&](size_t bytes) -> void* {
        void* p = ws + off;
        off += (bytes + 255) & ~(size_t)255;
        return p;
    };
    float* hA       = (float*)alloc((size_t)NN * DIM * 4);
    float* hB       = (float*)alloc((size_t)NN * DIM * 4);
    float* ssrc     = (float*)alloc((size_t)NN * 4);
    float* sdst     = (float*)alloc((size_t)NN * 4);
    int*   deg      = (int*)alloc((size_t)NN * 4);
    int*   row_ptr  = (int*)alloc((size_t)(NN + 1) * 4);
    int*   cursor   = (int*)alloc((size_t)NN * 4);
    int2*  sd_pairs = (int2*)alloc((size_t)NE * 8);
    int2*  w_pairs  = (int2*)alloc((size_t)NE * 8);
    int*   blocksum = (int*)alloc((size_t)SCAN_BLOCKS * 4);
    int*   blockoff = (int*)alloc((size_t)SCAN_BLOCKS * 4);

    // ---- build CSR (per launch; ws is re-poisoned between calls) ----
    hipMemsetAsync(deg, 0, (size_t)NN * 4, stream);
    hist_kernel<<<(NE + 255) / 256, 256, 0, stream>>>(src, deg);
    partial_kernel<<<SCAN_BLOCKS, 256, 0, stream>>>(deg, blocksum);
    scan_partials_kernel<<<1, 512, 0, stream>>>(blocksum, blockoff);
    rowptr_kernel<<<SCAN_BLOCKS, 256, 0, stream>>>(deg, blockoff, row_ptr, cursor);
    fill_kernel<<<(NE + 255) / 256, 256, 0, stream>>>(src, dst, cursor, sd_pairs);

    dim3 gemm_block(24, 8);
    int gemm_grid   = (NN + 63) / 64;                 // 1563
    int wave_blocks = ((NN * 64) + 255) / 256;        // 25000 (one wave per node)
    int edge_blocks = (NE + 255) / 256;               // 3125

    // ---- layer 1 ----
    gemm96_kernel<<<gemm_grid, gemm_block, 0, stream>>>(x, W1, hA, NN);
    dots_kernel<<<wave_blocks, 256, 0, stream>>>(hA, a1, ssrc, sdst);
    edgew_kernel<<<edge_blocks, 256, 0, stream>>>(sd_pairs, ssrc, sdst, w_pairs);
    agg_kernel<false><<<wave_blocks, 256, 0, stream>>>(hA, row_ptr, w_pairs, hB);

    // ---- layer 2 ----
    gemm96_kernel<<<gemm_grid, gemm_block, 0, stream>>>(hB, W2, hA, NN);
    dots_kernel<<<wave_blocks, 256, 0, stream>>>(hA, a2, ssrc, sdst);
    edgew_kernel<<<edge_blocks, 256, 0, stream>>>(sd_pairs, ssrc, sdst, w_pairs);
    agg_kernel<true><<<wave_blocks, 256, 0, stream>>>(hA, row_ptr, w_pairs, out);
}